// Round 19
// baseline (416.757 us; speedup 1.0000x reference)
//
#include <hip/hip_runtime.h>
#include <stdint.h>

#define DEV static __device__ __forceinline__

typedef __attribute__((ext_vector_type(8))) __bf16 bf16x8;
typedef __attribute__((ext_vector_type(4))) float f32x4;

DEV float bf2f(uint32_t u) {
  union { uint32_t i; float f; } v; v.i = u << 16; return v.f;
}
DEV uint16_t f2bf(float f) {
  union { float f; uint32_t i; } v; v.f = f;
  uint32_t x = v.i;
  return (uint16_t)((x + 0x7FFFu + ((x >> 16) & 1u)) >> 16);
}
DEV f32x4 mfma16(bf16x8 a, bf16x8 b, f32x4 c) {
  return __builtin_amdgcn_mfma_f32_16x16x32_bf16(a, b, c, 0, 0, 0);
}
DEV bf16x8 as_bf16x8(uint4 u) { return __builtin_bit_cast(bf16x8, u); }

DEV void gload16(const uint16_t* __restrict__ g, uint16_t* l) {
  __builtin_amdgcn_global_load_lds(
      (const __attribute__((address_space(1))) uint32_t*)g,
      (__attribute__((address_space(3))) uint32_t*)l, 16, 0, 0);
}

DEV float gelu_tanh(float x) {
  float x3 = x * x * x;
  float u = 0.7978845608028654f * (x + 0.044715f * x3);
  return 0.5f * x * (1.0f + tanhf(u));
}
DEV unsigned mono_key(float f) {
  union { float f; uint32_t u; } v; v.f = f;
  return (v.u & 0x80000000u) ? ~v.u : (v.u | 0x80000000u);
}
DEV unsigned mono16(unsigned u) {
  return (u & 0x8000u) ? (~u & 0xFFFFu) : (u | 0x8000u);
}

// ---------------- transpose + cast fp32 [R][C] -> bf16 hi(/lo) [C][R] ----------------
__global__ __launch_bounds__(256) void k_transpose_cast(
    const float* __restrict__ in, uint16_t* __restrict__ out,
    uint16_t* __restrict__ outlo, int R, int C) {
  __shared__ float tile[32][33];
  int c0 = blockIdx.x * 32, r0 = blockIdx.y * 32;
  int tx = threadIdx.x % 32, ty = threadIdx.x / 32;  // ty in 0..7
  for (int i = 0; i < 32; i += 8)
    tile[ty + i][tx] = in[(size_t)(r0 + ty + i) * C + c0 + tx];
  __syncthreads();
  for (int i = 0; i < 32; i += 8) {
    float v = tile[tx][ty + i];
    uint16_t hi = f2bf(v);
    out[(size_t)(c0 + ty + i) * R + r0 + tx] = hi;
    if (outlo)
      outlo[(size_t)(c0 + ty + i) * R + r0 + tx] = f2bf(v - bf2f(hi));
  }
}

// ---------------- elementwise cast fp32 -> bf16 ----------------
__global__ __launch_bounds__(256) void k_cast_bf16(
    const float* __restrict__ in, uint16_t* __restrict__ out, long n) {
  long i = ((long)blockIdx.x * 256 + threadIdx.x) * 4;
  if (i >= n) return;
  float4 v = *(const float4*)(in + i);
  uint2 pk;
  pk.x = (uint32_t)f2bf(v.x) | ((uint32_t)f2bf(v.y) << 16);
  pk.y = (uint32_t)f2bf(v.z) | ((uint32_t)f2bf(v.w) << 16);
  *(uint2*)(out + i) = pk;
}

// ---------------- LayerNorm row of 1024, fp32 in -> bf16 hi(/lo) out ----------------
__global__ __launch_bounds__(256) void k_layernorm(
    const float* __restrict__ x, const float* __restrict__ g,
    const float* __restrict__ bb, uint16_t* __restrict__ out,
    uint16_t* __restrict__ outlo) {
  int row = blockIdx.x;
  const float* xr = x + (size_t)row * 1024;
  int c = threadIdx.x * 4;
  float4 v = *(const float4*)(xr + c);
  float s = v.x + v.y + v.z + v.w;
  float s2 = v.x * v.x + v.y * v.y + v.z * v.z + v.w * v.w;
  for (int off = 32; off; off >>= 1) {
    s += __shfl_down(s, off, 64);
    s2 += __shfl_down(s2, off, 64);
  }
  __shared__ float ps[4], qs[4];
  int lane = threadIdx.x & 63, wv = threadIdx.x >> 6;
  if (!lane) { ps[wv] = s; qs[wv] = s2; }
  __syncthreads();
  float S = ps[0] + ps[1] + ps[2] + ps[3];
  float S2 = qs[0] + qs[1] + qs[2] + qs[3];
  float mu = S * (1.f / 1024.f);
  float var = S2 * (1.f / 1024.f) - mu * mu;
  float rinv = rsqrtf(var + 1e-5f);
  const float* vv = (const float*)&v;
  uint16_t o[4], ol[4];
#pragma unroll
  for (int j = 0; j < 4; j++) {
    float y = (vv[j] - mu) * rinv * g[c + j] + bb[c + j];
    o[j] = f2bf(y);
    ol[j] = f2bf(y - bf2f(o[j]));
  }
  uint2 pk;
  pk.x = (uint32_t)o[0] | ((uint32_t)o[1] << 16);
  pk.y = (uint32_t)o[2] | ((uint32_t)o[3] << 16);
  *(uint2*)(out + (size_t)row * 1024 + c) = pk;
  if (outlo) {
    pk.x = (uint32_t)ol[0] | ((uint32_t)ol[1] << 16);
    pk.y = (uint32_t)ol[2] | ((uint32_t)ol[3] << 16);
    *(uint2*)(outlo + (size_t)row * 1024 + c) = pk;
  }
}

// ======== bf16 MFMA GEMM, BM=64 x BN=128, BK=64 (16 MFMA/barrier-pair), swizzled ========
template <int EPI>
__global__ __launch_bounds__(256) void k_gemm2(
    const uint16_t* __restrict__ A, int lda,
    const uint16_t* __restrict__ Bt, int ldb,
    void* __restrict__ Cout, int ldc,
    const float* __restrict__ bias,
    const float* __restrict__ resid,
    int Kc) {
  const int m0 = blockIdx.y * 64, n0 = blockIdx.x * 128;
  const int kt0 = (EPI & 16) ? blockIdx.z * Kc : 0;
  __shared__ __align__(16) uint16_t As[64 * 64];    // 8 KB
  __shared__ __align__(16) uint16_t Bs[128 * 64];   // 16 KB
  const int t = threadIdx.x, l = t & 63, w = t >> 6;
  const int lg = l >> 4, lr = l & 15;

  const int rS = t >> 3, cS = t & 7;
  const int csS = cS ^ (rS & 7);
  const uint16_t* pa1 = A + (size_t)(m0 + rS) * lda + kt0 + csS * 8;
  const uint16_t* pa2 = pa1 + (size_t)32 * lda;
  const uint16_t* pb1 = Bt + (size_t)(n0 + rS) * ldb + kt0 + csS * 8;
  const uint16_t* pb2 = pb1 + (size_t)32 * ldb;
  const uint16_t* pb3 = pb1 + (size_t)64 * ldb;
  const uint16_t* pb4 = pb1 + (size_t)96 * ldb;
  uint16_t* la1 = As + w * 512;
  uint16_t* la2 = As + 2048 + w * 512;
  uint16_t* lb1 = Bs + w * 512;
  uint16_t* lb2 = Bs + 2048 + w * 512;
  uint16_t* lb3 = Bs + 4096 + w * 512;
  uint16_t* lb4 = Bs + 6144 + w * 512;

  int offA[2][4], offB[2][2];
#pragma unroll
  for (int kk = 0; kk < 2; kk++) {
#pragma unroll
    for (int i = 0; i < 4; i++) {
      int row = i * 16 + lr;
      offA[kk][i] = row * 64 + (((kk * 4 + lg) ^ (row & 7)) * 8);
    }
#pragma unroll
    for (int j = 0; j < 2; j++) {
      int row = w * 32 + j * 16 + lr;
      offB[kk][j] = row * 64 + (((kk * 4 + lg) ^ (row & 7)) * 8);
    }
  }

  f32x4 acc[4][2] = {};
  for (int kt = 0; kt < Kc; kt += 64) {
    __syncthreads();
    gload16(pa1, la1); gload16(pa2, la2);
    gload16(pb1, lb1); gload16(pb2, lb2);
    gload16(pb3, lb3); gload16(pb4, lb4);
    pa1 += 64; pa2 += 64; pb1 += 64; pb2 += 64; pb3 += 64; pb4 += 64;
    __syncthreads();
#pragma unroll
    for (int kk = 0; kk < 2; kk++) {
      bf16x8 af[4], bfr[2];
#pragma unroll
      for (int i = 0; i < 4; i++) af[i] = as_bf16x8(*(const uint4*)(As + offA[kk][i]));
#pragma unroll
      for (int j = 0; j < 2; j++) bfr[j] = as_bf16x8(*(const uint4*)(Bs + offB[kk][j]));
#pragma unroll
      for (int i = 0; i < 4; i++)
#pragma unroll
        for (int j = 0; j < 2; j++)
          acc[i][j] = mfma16(af[i], bfr[j], acc[i][j]);
    }
  }
  const size_t zoff = (EPI & 16) ? (size_t)blockIdx.z * gridDim.y * 64 * ldc : 0;
#pragma unroll
  for (int i = 0; i < 4; i++)
#pragma unroll
    for (int j = 0; j < 2; j++)
#pragma unroll
      for (int r = 0; r < 4; r++) {
        int row = m0 + i * 16 + lg * 4 + r;
        int col = n0 + w * 32 + j * 16 + lr;
        float v = acc[i][j][r];
        if constexpr (EPI & 16) {
          ((float*)Cout)[zoff + (size_t)row * ldc + col] = v;
        } else {
          if constexpr (EPI & 1) v += bias[col];
          if constexpr (EPI & 4) v = gelu_tanh(v);
          if constexpr (EPI & 2) v += resid[(size_t)row * ldc + col];
          if constexpr (EPI & 8)
            ((uint16_t*)Cout)[(size_t)row * ldc + col] = f2bf(v);
          else
            ((float*)Cout)[(size_t)row * ldc + col] = v;
        }
      }
}

// ======== sims GEMM: BM=64 x BN=128, BK=64, bf16 out, batched (z in {0,1}) ========
__global__ __launch_bounds__(256) void k_gemm_sims(
    const uint16_t* __restrict__ A,
    const uint16_t* __restrict__ Bt,
    uint16_t* __restrict__ Cout) {
  const int m0 = blockIdx.y * 64, n0 = blockIdx.x * 128;
  A += (size_t)blockIdx.z * 1024 * 3072;
  Bt += (size_t)blockIdx.z * 8192 * 1024;
  __shared__ __align__(16) uint16_t As[64 * 64];    // 8 KB
  __shared__ __align__(16) uint16_t Bs[128 * 64];   // 16 KB
  const int t = threadIdx.x, l = t & 63, w = t >> 6;
  const int lg = l >> 4, lr = l & 15;

  const int rS = t >> 3, cS = t & 7;
  const int csS = cS ^ (rS & 7);
  const uint16_t* pa1 = A + (size_t)(m0 + rS) * 3072 + csS * 8;
  const uint16_t* pa2 = pa1 + 32 * 3072;
  const uint16_t* pb1 = Bt + (size_t)(n0 + rS) * 1024 + csS * 8;
  const uint16_t* pb2 = pb1 + 32 * 1024;
  const uint16_t* pb3 = pb1 + 64 * 1024;
  const uint16_t* pb4 = pb1 + 96 * 1024;
  uint16_t* la1 = As + w * 512;
  uint16_t* la2 = As + 2048 + w * 512;
  uint16_t* lb1 = Bs + w * 512;
  uint16_t* lb2 = Bs + 2048 + w * 512;
  uint16_t* lb3 = Bs + 4096 + w * 512;
  uint16_t* lb4 = Bs + 6144 + w * 512;

  int offA[2][4], offB[2][2];
#pragma unroll
  for (int kk = 0; kk < 2; kk++) {
#pragma unroll
    for (int i = 0; i < 4; i++) {
      int row = i * 16 + lr;
      offA[kk][i] = row * 64 + (((kk * 4 + lg) ^ (row & 7)) * 8);
    }
#pragma unroll
    for (int j = 0; j < 2; j++) {
      int row = w * 32 + j * 16 + lr;
      offB[kk][j] = row * 64 + (((kk * 4 + lg) ^ (row & 7)) * 8);
    }
  }

  f32x4 acc[4][2] = {};
  for (int kt = 0; kt < 1024; kt += 64) {
    __syncthreads();
    gload16(pa1, la1); gload16(pa2, la2);
    gload16(pb1, lb1); gload16(pb2, lb2);
    gload16(pb3, lb3); gload16(pb4, lb4);
    pa1 += 64; pa2 += 64; pb1 += 64; pb2 += 64; pb3 += 64; pb4 += 64;
    __syncthreads();
#pragma unroll
    for (int kk = 0; kk < 2; kk++) {
      bf16x8 af[4], bfr[2];
#pragma unroll
      for (int i = 0; i < 4; i++) af[i] = as_bf16x8(*(const uint4*)(As + offA[kk][i]));
#pragma unroll
      for (int j = 0; j < 2; j++) bfr[j] = as_bf16x8(*(const uint4*)(Bs + offB[kk][j]));
#pragma unroll
      for (int i = 0; i < 4; i++)
#pragma unroll
        for (int j = 0; j < 2; j++)
          acc[i][j] = mfma16(af[i], bfr[j], acc[i][j]);
    }
  }
  const size_t zoff = (size_t)blockIdx.z * 1024 * 8192;
#pragma unroll
  for (int i = 0; i < 4; i++)
#pragma unroll
    for (int j = 0; j < 2; j++)
#pragma unroll
      for (int r = 0; r < 4; r++) {
        int row = m0 + i * 16 + lg * 4 + r;
        int col = n0 + w * 32 + j * 16 + lr;
        Cout[zoff + (size_t)row * 8192 + col] = f2bf(acc[i][j][r]);
      }
}

// ------- split-precision GEMM (3-term), BM=64 x BN=128, BK=64, gload_lds, swizzled -------
__global__ __launch_bounds__(256) void k_gemm_split2(
    const uint16_t* __restrict__ Ah, const uint16_t* __restrict__ Al, int lda,
    const uint16_t* __restrict__ Bh, const uint16_t* __restrict__ Bl, int ldb,
    uint16_t* __restrict__ Ch, uint16_t* __restrict__ Cl, int ldc,
    const float* __restrict__ bias, int Kd) {
  const int m0 = blockIdx.y * 64, n0 = blockIdx.x * 128;
  __shared__ __align__(16) uint16_t Ahs[64 * 64];
  __shared__ __align__(16) uint16_t Als[64 * 64];
  __shared__ __align__(16) uint16_t Bhs[128 * 64];
  __shared__ __align__(16) uint16_t Bls[128 * 64];
  const int t = threadIdx.x, l = t & 63, w = t >> 6;
  const int lg = l >> 4, lr = l & 15;

  const int rS = t >> 3, cS = t & 7;
  const int csS = cS ^ (rS & 7);
  const size_t ao1 = (size_t)(m0 + rS) * lda + csS * 8;
  const size_t bo1 = (size_t)(n0 + rS) * ldb + csS * 8;
  const uint16_t* pah1 = Ah + ao1; const uint16_t* pah2 = pah1 + (size_t)32 * lda;
  const uint16_t* pal1 = Al + ao1; const uint16_t* pal2 = pal1 + (size_t)32 * lda;
  const uint16_t* pbh1 = Bh + bo1; const uint16_t* pbh2 = pbh1 + (size_t)32 * ldb;
  const uint16_t* pbh3 = pbh1 + (size_t)64 * ldb; const uint16_t* pbh4 = pbh1 + (size_t)96 * ldb;
  const uint16_t* pbl1 = Bl + bo1; const uint16_t* pbl2 = pbl1 + (size_t)32 * ldb;
  const uint16_t* pbl3 = pbl1 + (size_t)64 * ldb; const uint16_t* pbl4 = pbl1 + (size_t)96 * ldb;
  uint16_t* lah1 = Ahs + w * 512; uint16_t* lah2 = Ahs + 2048 + w * 512;
  uint16_t* lal1 = Als + w * 512; uint16_t* lal2 = Als + 2048 + w * 512;
  uint16_t* lbh1 = Bhs + w * 512; uint16_t* lbh2 = Bhs + 2048 + w * 512;
  uint16_t* lbh3 = Bhs + 4096 + w * 512; uint16_t* lbh4 = Bhs + 6144 + w * 512;
  uint16_t* lbl1 = Bls + w * 512; uint16_t* lbl2 = Bls + 2048 + w * 512;
  uint16_t* lbl3 = Bls + 4096 + w * 512; uint16_t* lbl4 = Bls + 6144 + w * 512;

  int offA[2][4], offB[2][2];
#pragma unroll
  for (int kk = 0; kk < 2; kk++) {
#pragma unroll
    for (int i = 0; i < 4; i++) {
      int row = i * 16 + lr;
      offA[kk][i] = row * 64 + (((kk * 4 + lg) ^ (row & 7)) * 8);
    }
#pragma unroll
    for (int j = 0; j < 2; j++) {
      int row = w * 32 + j * 16 + lr;
      offB[kk][j] = row * 64 + (((kk * 4 + lg) ^ (row & 7)) * 8);
    }
  }

  f32x4 acc[4][2] = {};
  for (int kt = 0; kt < Kd; kt += 64) {
    __syncthreads();
    gload16(pah1, lah1); gload16(pah2, lah2);
    gload16(pal1, lal1); gload16(pal2, lal2);
    gload16(pbh1, lbh1); gload16(pbh2, lbh2);
    gload16(pbh3, lbh3); gload16(pbh4, lbh4);
    gload16(pbl1, lbl1); gload16(pbl2, lbl2);
    gload16(pbl3, lbl3); gload16(pbl4, lbl4);
    pah1 += 64; pah2 += 64; pal1 += 64; pal2 += 64;
    pbh1 += 64; pbh2 += 64; pbh3 += 64; pbh4 += 64;
    pbl1 += 64; pbl2 += 64; pbl3 += 64; pbl4 += 64;
    __syncthreads();
#pragma unroll
    for (int kk = 0; kk < 2; kk++) {
      bf16x8 ah[4], al[4], bh[2], bl[2];
#pragma unroll
      for (int i = 0; i < 4; i++) {
        ah[i] = as_bf16x8(*(const uint4*)(Ahs + offA[kk][i]));
        al[i] = as_bf16x8(*(const uint4*)(Als + offA[kk][i]));
      }
#pragma unroll
      for (int j = 0; j < 2; j++) {
        bh[j] = as_bf16x8(*(const uint4*)(Bhs + offB[kk][j]));
        bl[j] = as_bf16x8(*(const uint4*)(Bls + offB[kk][j]));
      }
#pragma unroll
      for (int i = 0; i < 4; i++)
#pragma unroll
        for (int j = 0; j < 2; j++) {
          acc[i][j] = mfma16(ah[i], bh[j], acc[i][j]);
          acc[i][j] = mfma16(ah[i], bl[j], acc[i][j]);
          acc[i][j] = mfma16(al[i], bh[j], acc[i][j]);
        }
    }
  }
#pragma unroll
  for (int i = 0; i < 4; i++)
#pragma unroll
    for (int j = 0; j < 2; j++)
#pragma unroll
      for (int r = 0; r < 4; r++) {
        int row = m0 + i * 16 + lg * 4 + r;
        int col = n0 + w * 32 + j * 16 + lr;
        float v = acc[i][j][r] + bias[col];
        uint16_t hi = f2bf(v);
        Ch[(size_t)row * ldc + col] = hi;
        Cl[(size_t)row * ldc + col] = f2bf(v - bf2f(hi));
      }
}

// ---------------- split-K merge: out = sum(parts) + bias + resid (f32) ----------------
template <int NP>
__global__ __launch_bounds__(256) void k_merge(
    const float* __restrict__ parts, const float* __restrict__ bias,
    const float* __restrict__ resid, float* __restrict__ out) {
  int row = blockIdx.x, c = threadIdx.x * 4;
  size_t off = (size_t)row * 1024 + c;
  float4 s = *(const float4*)(resid + off);
  float4 bv = *(const float4*)(bias + c);
  s.x += bv.x; s.y += bv.y; s.z += bv.z; s.w += bv.w;
#pragma unroll
  for (int z = 0; z < NP; z++) {
    float4 pv = *(const float4*)(parts + (size_t)z * 2048 * 1024 + off);
    s.x += pv.x; s.y += pv.y; s.z += pv.z; s.w += pv.w;
  }
  *(float4*)(out + off) = s;
}

// ================== FUSED topk2 + flash (INTERLEAVED block ids) ==================
// id&1==0 -> topk2 body (row = id>>1); id&1==1 -> flash body (id>>1).
// Interleaving keeps both workload types co-resident on every CU for true overlap.

DEV void topk2_body(
    char* smem, int grow,
    const uint16_t* __restrict__ simsb,
    const uint16_t* __restrict__ qkvh_b,
    const uint16_t* __restrict__ qkvl_b,
    const float* __restrict__ memk_b,
    int* __restrict__ idx_out,
    float* __restrict__ mlogh) {
  int z = grow >> 10;
  int t = threadIdx.x;
  const uint16_t* s16 = simsb + (size_t)grow * 8192;
  const float* memk = memk_b + (size_t)z * 8192 * 1024;
  int* partial = (int*)smem;                 // [2][4]
  int* cnt_s = (int*)(smem + 32);
  int* sidx = (int*)(smem + 64);             // [40]
  float* qs = (float*)(smem + 256);          // [1024]
  float* hval = (float*)(smem + 4352);       // [40][16]
  unsigned key[32];
#pragma unroll
  for (int k = 0; k < 4; k++) {
    uint4 u = *(const uint4*)(s16 + t * 8 + k * 2048);
    const uint16_t* pu = (const uint16_t*)&u;
#pragma unroll
    for (int j = 0; j < 8; j++) key[k * 8 + j] = mono16(pu[j]);
  }
  int lane = t & 63, wv = t >> 6;
  unsigned lo = 0u, hi = 0xFFFFu;
  for (int it = 0; it < 16; ++it) {
    unsigned mid = lo + ((hi - lo) >> 1);
    int c = 0;
#pragma unroll
    for (int i = 0; i < 32; i++) c += (key[i] > mid) ? 1 : 0;
    for (int off = 32; off; off >>= 1) c += __shfl_down(c, off, 64);
    if (!lane) partial[(it & 1) * 4 + wv] = c;
    __syncthreads();
    int tot = partial[(it & 1) * 4 + 0] + partial[(it & 1) * 4 + 1] +
              partial[(it & 1) * 4 + 2] + partial[(it & 1) * 4 + 3];
    if (tot >= 40) lo = mid + 1; else hi = mid;
  }
  unsigned T = lo;
  if (t == 0) *cnt_s = 0;
  __syncthreads();
#pragma unroll
  for (int i = 0; i < 32; i++)
    if (key[i] > T) {
      int p = atomicAdd(cnt_s, 1);
      if (p < 40) sidx[p] = t * 8 + (i >> 3) * 2048 + (i & 7);
    }
  __syncthreads();
#pragma unroll
  for (int i = 0; i < 32; i++)
    if (key[i] == T) {
      int p = atomicAdd(cnt_s, 1);
      if (p < 40) sidx[p] = t * 8 + (i >> 3) * 2048 + (i & 7);
    }
  {
    int c4 = t * 4;
    const uint16_t* qh = qkvh_b + (size_t)grow * 3072;
    const uint16_t* ql = qkvl_b + (size_t)grow * 3072;
    uint2 uh = *(const uint2*)(qh + c4);
    uint2 ul = *(const uint2*)(ql + c4);
    qs[c4 + 0] = bf2f(uh.x & 0xFFFF) + bf2f(ul.x & 0xFFFF);
    qs[c4 + 1] = bf2f(uh.x >> 16) + bf2f(ul.x >> 16);
    qs[c4 + 2] = bf2f(uh.y & 0xFFFF) + bf2f(ul.y & 0xFFFF);
    qs[c4 + 3] = bf2f(uh.y >> 16) + bf2f(ul.y >> 16);
  }
  __syncthreads();
  {
    float4 qreg[4];
#pragma unroll
    for (int i = 0; i < 4; i++) qreg[i] = *(const float4*)(qs + i * 256 + lane * 4);
    for (int cc = 0; cc < 10; ++cc) {
      int c = wv * 10 + cc;
      const float* kp = memk + (size_t)sidx[c] * 1024;
#pragma unroll
      for (int i = 0; i < 4; ++i) {
        float4 kv = *(const float4*)(kp + i * 256 + lane * 4);
        float pband = kv.x * qreg[i].x + kv.y * qreg[i].y +
                      kv.z * qreg[i].z + kv.w * qreg[i].w;
        pband += __shfl_xor(pband, 1, 64);
        pband += __shfl_xor(pband, 2, 64);
        pband += __shfl_xor(pband, 4, 64);
        pband += __shfl_xor(pband, 8, 64);
        if ((lane & 15) == 0) hval[c * 16 + i * 4 + (lane >> 4)] = pband;
      }
    }
  }
  __syncthreads();
  if (wv == 0) {
    float full = 0.f;
    if (t < 40) {
#pragma unroll
      for (int i = 0; i < 16; i++) full += hval[t * 16 + i];
    }
    unsigned k2 = (t < 40) ? mono_key(full) : 0u;
    unsigned lo2 = 0u, hi2 = 0xFFFFFFFFu;
    for (int it = 0; it < 32; ++it) {
      unsigned mid = lo2 + ((hi2 - lo2) >> 1);
      int c = __popcll(__ballot(k2 > mid));
      if (c >= 32) lo2 = mid + 1; else hi2 = mid;
    }
    unsigned T2 = lo2;
    unsigned long long m1 = __ballot(k2 > T2);
    unsigned long long m2 = __ballot(k2 == T2);
    int n1 = __popcll(m1);
    unsigned long long lt = ((unsigned long long)1 << t) - 1;
    int pos = 99;
    if (k2 > T2) pos = __popcll(m1 & lt);
    else if (k2 == T2 && t < 40) pos = n1 + __popcll(m2 & lt);
    if (pos < 32) {
      idx_out[(size_t)grow * 32 + pos] = sidx[t];
#pragma unroll
      for (int i = 0; i < 16; i++)
        mlogh[((size_t)grow * 32 + pos) * 16 + i] = hval[t * 16 + i] * 0.125f;
    }
  }
}

DEV void flash_body(
    char* smem, int id,
    const uint16_t* __restrict__ qkvh,
    const uint16_t* __restrict__ qkvl,
    float* __restrict__ pacc,
    float* __restrict__ pm,
    float* __restrict__ pl) {
  const int qt = id & 15, chk = (id >> 4) & 3, bh = id >> 6;
  const int cbase = chk * 256;
  if (cbase >= (qt + 1) * 64) return;
  const int b = bh >> 4, h = bh & 15;
  const int t = threadIdx.x, lane = t & 63, w = t >> 6;
  const int lg = lane >> 4, lr = lane & 15;
  const int q0 = qt * 64 + w * 16;
  const size_t rowb = (size_t)b * 1024;
  uint16_t* Kh = (uint16_t*)smem;               // [32][64] 4 KB
  uint16_t* Kl = (uint16_t*)(smem + 4096);
  uint16_t* Vs = (uint16_t*)(smem + 8192);
  uint16_t* Pl = (uint16_t*)(smem + 12288);     // [4][16][40] 5 KB

  bf16x8 qh[2], qlo[2];
  {
    const uint16_t* qph = qkvh + (rowb + q0 + lr) * 3072 + h * 64;
    const uint16_t* qpl = qkvl + (rowb + q0 + lr) * 3072 + h * 64;
    qh[0] = as_bf16x8(*(const uint4*)(qph + lg * 8));
    qh[1] = as_bf16x8(*(const uint4*)(qph + 32 + lg * 8));
    qlo[0] = as_bf16x8(*(const uint4*)(qpl + lg * 8));
    qlo[1] = as_bf16x8(*(const uint4*)(qpl + 32 + lg * 8));
  }
  f32x4 acc[4] = {};
  float mrow[4], lrowv[4];
#pragma unroll
  for (int r = 0; r < 4; r++) { mrow[r] = -1e30f; lrowv[r] = 0.f; }

  const int lim = min(cbase + 256, q0 + 16);
  const int blim = min(cbase + 256, (qt + 1) * 64);

  const int sr = t >> 3, sc = t & 7;
  const int scs = sc ^ (sr & 7);
  const uint16_t* gkh = qkvh + (rowb + sr) * 3072 + 1024 + h * 64 + scs * 8;
  const uint16_t* gkl = qkvl + (rowb + sr) * 3072 + 1024 + h * 64 + scs * 8;
  const uint16_t* gv  = qkvh + (rowb + sr) * 3072 + 2048 + h * 64 + scs * 8;
  uint16_t* lkh = Kh + w * 512;
  uint16_t* lkl = Kl + w * 512;
  uint16_t* lv  = Vs + w * 512;

  for (int c0 = cbase; c0 < blim; c0 += 32) {
    const size_t so = (size_t)c0 * 3072;
    gload16(gkh + so, lkh);
    gload16(gkl + so, lkl);
    gload16(gv + so, lv);
    __syncthreads();
    if (c0 < lim) {
      f32x4 sf[2];
#pragma unroll
      for (int n = 0; n < 2; n++) {
        const int row = n * 16 + lr;
        const int rb = row * 64;
        const int x0 = ((lg) ^ (row & 7)) * 8;
        const int x1 = ((4 + lg) ^ (row & 7)) * 8;
        bf16x8 kh0 = as_bf16x8(*(const uint4*)(Kh + rb + x0));
        bf16x8 kh1 = as_bf16x8(*(const uint4*)(Kh + rb + x1));
        bf16x8 kl0 = as_bf16x8(*(const uint4*)(Kl + rb + x0));
        bf16x8 kl1 = as_bf16x8(*(const uint4*)(Kl + rb + x1));
        f32x4 sz = {};
        sz = mfma16(qh[0], kh0, sz);
        sz = mfma16(qh[1], kh1, sz);
        sz = mfma16(qh[0], kl0, sz);
        sz = mfma16(qh[1], kl1, sz);
        sz = mfma16(qlo[0], kh0, sz);
        sz = mfma16(qlo[1], kh1, sz);
        sf[n] = sz;
      }
      float p0[4], p1[4], alpha[4];
#pragma unroll
      for (int r = 0; r < 4; r++) {
        int rowq = q0 + lg * 4 + r;
        int col0 = c0 + lr, col1 = c0 + 16 + lr;
        float s0 = sf[0][r] * 0.125f; if (col0 > rowq) s0 = -1e30f;
        float s1 = sf[1][r] * 0.125f; if (col1 > rowq) s1 = -1e30f;
        float mt = fmaxf(s0, s1);
        mt = fmaxf(mt, __shfl_xor(mt, 1, 64));
        mt = fmaxf(mt, __shfl_xor(mt, 2, 64));
        mt = fmaxf(mt, __shfl_xor(mt, 4, 64));
        mt = fmaxf(mt, __shfl_xor(mt, 8, 64));
        float mnew = fmaxf(mrow[r], mt);
        float a = __expf(mrow[r] - mnew);
        float e0 = __expf(s0 - mnew), e1 = __expf(s1 - mnew);
        float ss = e0 + e1;
        ss += __shfl_xor(ss, 1, 64);
        ss += __shfl_xor(ss, 2, 64);
        ss += __shfl_xor(ss, 4, 64);
        ss += __shfl_xor(ss, 8, 64);
        lrowv[r] = lrowv[r] * a + ss;
        mrow[r] = mnew;
        alpha[r] = a;
        p0[r] = e0; p1[r] = e1;
      }
#pragma unroll
      for (int nv = 0; nv < 4; nv++)
#pragma unroll
        for (int r = 0; r < 4; r++) acc[nv][r] *= alpha[r];
#pragma unroll
      for (int r = 0; r < 4; r++) {
        Pl[(w * 16 + lg * 4 + r) * 40 + lr] = f2bf(p0[r]);
        Pl[(w * 16 + lg * 4 + r) * 40 + 16 + lr] = f2bf(p1[r]);
      }
      bf16x8 pa = as_bf16x8(*(const uint4*)&Pl[(w * 16 + lr) * 40 + lg * 8]);
#pragma unroll
      for (int nv = 0; nv < 4; nv++) {
        const int col = nv * 16 + lr;
        const int cc = col >> 3, cl = col & 7;
        uint32_t vv[8];
#pragma unroll
        for (int j = 0; j < 8; j++) {
          int row = lg * 8 + j;
          vv[j] = Vs[row * 64 + ((cc ^ (row & 7)) * 8 + cl)];
        }
        uint4 pk;
        pk.x = vv[0] | (vv[1] << 16);
        pk.y = vv[2] | (vv[3] << 16);
        pk.z = vv[4] | (vv[5] << 16);
        pk.w = vv[6] | (vv[7] << 16);
        acc[nv] = mfma16(pa, as_bf16x8(pk), acc[nv]);
      }
    }
    __syncthreads();
  }
  const size_t base = (size_t)(chk * 32 + bh) * 1024;
#pragma unroll
  for (int nv = 0; nv < 4; nv++)
#pragma unroll
    for (int r = 0; r < 4; r++) {
      int rowq = q0 + lg * 4 + r;
      pacc[(base + rowq) * 64 + nv * 16 + lr] = acc[nv][r];
    }
  if (lr == 0) {
#pragma unroll
    for (int r = 0; r < 4; r++) {
      int rowq = q0 + lg * 4 + r;
      pm[base + rowq] = mrow[r];
      pl[base + rowq] = lrowv[r];
    }
  }
}

__global__ __launch_bounds__(256) void k_fused(
    const uint16_t* __restrict__ simsb,
    const uint16_t* __restrict__ qkvh,
    const uint16_t* __restrict__ qkvl,
    const float* __restrict__ memk_b,
    int* __restrict__ idx_out,
    float* __restrict__ mlogh,
    float* __restrict__ pacc,
    float* __restrict__ pm,
    float* __restrict__ pl) {
  __shared__ __align__(16) char smem[17536];
  if ((blockIdx.x & 1) == 0)
    topk2_body(smem, blockIdx.x >> 1, simsb, qkvh, qkvl, memk_b, idx_out, mlogh);
  else
    flash_body(smem, blockIdx.x >> 1, qkvh, qkvl, pacc, pm, pl);
}

// ------- mem attention (precomputed logits) + chunk-merge of local + combine -------
__global__ __launch_bounds__(256) void k_memcombine(
    const float* __restrict__ mlogh,     // [2048][32][16]
    const float* __restrict__ memv,      // f32  [B][8192][1024]
    const int* __restrict__ idx,         // [2048][32]
    const float* __restrict__ pacc,      // [4][32][1024][64]
    const float* __restrict__ pm,        // [4][32][1024]
    const float* __restrict__ pl,        // [4][32][1024]
    const float* __restrict__ gval,
    uint16_t* __restrict__ attnout) {
  int row = blockIdx.x;
  int b = row >> 10, s = row & 1023;
  int qt = s >> 6;
  int nact = (qt >> 2) + 1;
  __shared__ int sidx[32];
  __shared__ float lg[16][32];
  __shared__ float sp[16][32];
  __shared__ float smx[16], ssum[16];
  __shared__ float scl[16][4], Ms[16], Ls[16];
  int t = threadIdx.x;
  if (t < 32) sidx[t] = idx[(size_t)row * 32 + t];
  {
    const float* mp = mlogh + (size_t)row * 512;
#pragma unroll
    for (int rep = 0; rep < 2; rep++) {
      int i = t + rep * 256;
      lg[i & 15][i >> 4] = mp[i];
    }
  }
  __syncthreads();
  if (t < 16) {
    float mx = -1e30f;
#pragma unroll
    for (int j = 0; j < 32; j++) mx = fmaxf(mx, lg[t][j]);
    float su = 0.f;
    for (int j = 0; j < 32; j++) {
      float e = __expf(lg[t][j] - mx);
      sp[t][j] = e; su += e;
    }
    smx[t] = mx; ssum[t] = su;
  } else if (t >= 64 && t < 80) {
    int hh = t - 64;
    float pmv[4];
    float M = -1e30f;
    for (int c = 0; c < nact; c++) {
      pmv[c] = pm[(size_t)(c * 32 + b * 16 + hh) * 1024 + s];
      M = fmaxf(M, pmv[c]);
    }
    float L = 0.f;
    for (int c = 0; c < nact; c++) {
      float e = __expf(pmv[c] - M);
      scl[hh][c] = e;
      L += e * pl[(size_t)(c * 32 + b * 16 + hh) * 1024 + s];
    }
    Ms[hh] = M; Ls[hh] = L;
  }
  __syncthreads();
#pragma unroll
  for (int cc = 0; cc < 4; cc++) {
    int col = t + cc * 256;
    int hh = col >> 6;
    float ma = 0.f;
#pragma unroll
    for (int j = 0; j < 32; j++)
      ma += sp[hh][j] * memv[((size_t)b * 8192 + sidx[j]) * 1024 + col];
    float la = 0.f;
    for (int c = 0; c < nact; c++)
      la += scl[hh][c] *
            pacc[((size_t)(c * 32 + b * 16 + hh) * 1024 + s) * 64 + (col & 63)];
    float ms = Ms[hh], ls = Ls[hh];
    float mm = smx[hh], lmm = ssum[hh];
    float Mx = fmaxf(ms, mm);
    float es = __expf(ms - Mx), em = __expf(mm - Mx);
    float L = es * ls + em * lmm;
    float gh = gval[hh];
    float o = ((1.f - gh) * es * la + gh * em * ma) / L;
    attnout[(size_t)row * 1024 + col] = f2bf(o);
  }
}

extern "C" void kernel_launch(void* const* d_in, const int* in_sizes, int n_in,
                              void* d_out, int out_size, void* d_ws, size_t ws_size,
                              hipStream_t stream) {
  (void)in_sizes; (void)n_in; (void)out_size; (void)ws_size;
  const float* x     = (const float*)d_in[0];
  const float* memkf = (const float*)d_in[1];
  const float* memvf = (const float*)d_in[2];
  const float* gval  = (const float*)d_in[3];
  const float* ln1g  = (const float*)d_in[4];
  const float* ln1b  = (const float*)d_in[5];
  const float* Wattn = (const float*)d_in[6];
  const float* battn = (const float*)d_in[7];
  const float* Wproj = (const float*)d_in[8];
  const float* bproj = (const float*)d_in[9];
  const float* ln2g  = (const float*)d_in[10];
  const float* ln2b  = (const float*)d_in[11];
  const float* Wfc   = (const float*)d_in[12];
  const float* bfc   = (const float*)d_in[13];
  const float* Wout  = (const float*)d_in[14];
  const float* bout  = (const float*)d_in[15];

  char* p = (char*)d_ws;
  auto alloc = [&](size_t bytes) -> char* {
    char* r = p;
    p += (bytes + 255) & ~(size_t)255;
    return r;
  };
  uint16_t* h_hi    = (uint16_t*)alloc(2048ull * 1024 * 2);   // reused as h2
  uint16_t* h_lo    = (uint16_t*)alloc(2048ull * 1024 * 2);
  uint16_t* WattnTh = (uint16_t*)alloc(3072ull * 1024 * 2);
  uint16_t* WattnTl = (uint16_t*)alloc(3072ull * 1024 * 2);
  uint16_t* WprojT  = (uint16_t*)alloc(1024ull * 1024 * 2);
  uint16_t* WfcT    = (uint16_t*)alloc(4096ull * 1024 * 2);
  uint16_t* WoutT   = (uint16_t*)alloc(1024ull * 4096 * 2);
  uint16_t* memk_bf = (uint16_t*)alloc(2ull * 8192 * 1024 * 2);  // reused: pacc, parts
  uint16_t* qkv_hi  = (uint16_t*)alloc(2048ull * 3072 * 2);
  uint16_t* qkv_lo  = (uint16_t*)alloc(2048ull * 3072 * 2);
  float*    sims    = (float*)alloc(1024ull * 8192 * 4);  // bf16 sims both batches; reused: ffn1
  int*      idx     = (int*)alloc(2048ull * 32 * 4);
  float*    mlogh   = (float*)alloc(2048ull * 32 * 16 * 4);
  float*    pm      = (float*)alloc(4ull * 32 * 1024 * 4);
  float*    pl      = (float*)alloc(4ull * 32 * 1024 * 4);
  float*    h1      = (float*)alloc(2048ull * 1024 * 4);
  uint16_t* attn_bf = (uint16_t*)alloc(2048ull * 1024 * 2);
  uint16_t* h2_bf   = h_hi;
  uint16_t* simsb   = (uint16_t*)sims;   // bf16 sims (alive through k_fused)
  float*    pacc    = (float*)memk_bf;   // 32 MB; alive: k_fused .. memcombine
  uint16_t* ffn1    = (uint16_t*)sims;   // alive: after memcombine
  float*    parts   = (float*)memk_bf;   // alive: after memcombine (proj/out split-K)

  // weight prep
  k_transpose_cast<<<dim3(96, 32), 256, 0, stream>>>(Wattn, WattnTh, WattnTl, 1024, 3072);
  k_transpose_cast<<<dim3(32, 32), 256, 0, stream>>>(Wproj, WprojT, nullptr, 1024, 1024);
  k_transpose_cast<<<dim3(128, 32), 256, 0, stream>>>(Wfc, WfcT, nullptr, 1024, 4096);
  k_transpose_cast<<<dim3(32, 128), 256, 0, stream>>>(Wout, WoutT, nullptr, 4096, 1024);
  k_cast_bf16<<<16384, 256, 0, stream>>>(memkf, memk_bf, 2l * 8192 * 1024);

  // LN1 + QKV (split precision, BK=64)
  k_layernorm<<<2048, 256, 0, stream>>>(x, ln1g, ln1b, h_hi, h_lo);
  k_gemm_split2<<<dim3(24, 32), 256, 0, stream>>>(h_hi, h_lo, 1024, WattnTh, WattnTl, 1024,
                                                  qkv_hi, qkv_lo, 3072, battn, 1024);
  // sims (bf16 out, BOTH batches, BK=64)
  k_gemm_sims<<<dim3(64, 16, 2), 256, 0, stream>>>(qkv_hi, memk_bf, simsb);
  // FUSED interleaved: even ids -> topk2, odd ids -> flash; memk_bf now dead -> pacc
  k_fused<<<4096, 256, 0, stream>>>(simsb, qkv_hi, qkv_lo, memkf, idx, mlogh, pacc, pm, pl);
  k_memcombine<<<2048, 256, 0, stream>>>(mlogh, memvf, idx, pacc, pm, pl, gval, attn_bf);
  // proj + residual  (split-K=2 -> parts, then merge with bias + x)
  k_gemm2<16><<<dim3(8, 32, 2), 256, 0, stream>>>(attn_bf, 1024, WprojT, 1024,
                                                  parts, 1024, nullptr, nullptr, 512);
  k_merge<2><<<2048, 256, 0, stream>>>(parts, bproj, x, h1);
  // FFN (sims region now free -> ffn1)
  k_layernorm<<<2048, 256, 0, stream>>>(h1, ln2g, ln2b, h2_bf, nullptr);
  k_gemm2<13><<<dim3(32, 32), 256, 0, stream>>>(h2_bf, 1024, WfcT, 1024,
                                                ffn1, 4096, bfc, nullptr, 1024);
  // out GEMM (K=4096, split-K=4 -> parts, merge with bias + h1 residual)
  k_gemm2<16><<<dim3(8, 32, 4), 256, 0, stream>>>(ffn1, 4096, WoutT, 4096,
                                                  parts, 1024, nullptr, nullptr, 1024);
  k_merge<4><<<2048, 256, 0, stream>>>(parts, bout, h1, (float*)d_out);
}

// Round 20
// 396.092 us; speedup vs baseline: 1.0522x; 1.0522x over previous
//
#include <hip/hip_runtime.h>
#include <stdint.h>

#define DEV static __device__ __forceinline__

typedef __attribute__((ext_vector_type(8))) __bf16 bf16x8;
typedef __attribute__((ext_vector_type(4))) float f32x4;

DEV float bf2f(uint32_t u) {
  union { uint32_t i; float f; } v; v.i = u << 16; return v.f;
}
DEV uint16_t f2bf(float f) {
  union { float f; uint32_t i; } v; v.f = f;
  uint32_t x = v.i;
  return (uint16_t)((x + 0x7FFFu + ((x >> 16) & 1u)) >> 16);
}
DEV f32x4 mfma16(bf16x8 a, bf16x8 b, f32x4 c) {
  return __builtin_amdgcn_mfma_f32_16x16x32_bf16(a, b, c, 0, 0, 0);
}
DEV bf16x8 as_bf16x8(uint4 u) { return __builtin_bit_cast(bf16x8, u); }

DEV void gload16(const uint16_t* __restrict__ g, uint16_t* l) {
  __builtin_amdgcn_global_load_lds(
      (const __attribute__((address_space(1))) uint32_t*)g,
      (__attribute__((address_space(3))) uint32_t*)l, 16, 0, 0);
}

DEV float gelu_tanh(float x) {
  float x3 = x * x * x;
  float u = 0.7978845608028654f * (x + 0.044715f * x3);
  return 0.5f * x * (1.0f + tanhf(u));
}
DEV unsigned mono_key(float f) {
  union { float f; uint32_t u; } v; v.f = f;
  return (v.u & 0x80000000u) ? ~v.u : (v.u | 0x80000000u);
}
// 16-bit monotone key on a raw bf16 pattern (order-isomorphic to float compare)
DEV unsigned mono16(unsigned u) {
  return (u & 0x8000u) ? (~u & 0xFFFFu) : (u | 0x8000u);
}

// ---------------- transpose + cast fp32 [R][C] -> bf16 hi(/lo) [C][R] ----------------
__global__ __launch_bounds__(256) void k_transpose_cast(
    const float* __restrict__ in, uint16_t* __restrict__ out,
    uint16_t* __restrict__ outlo, int R, int C) {
  __shared__ float tile[32][33];
  int c0 = blockIdx.x * 32, r0 = blockIdx.y * 32;
  int tx = threadIdx.x % 32, ty = threadIdx.x / 32;  // ty in 0..7
  for (int i = 0; i < 32; i += 8)
    tile[ty + i][tx] = in[(size_t)(r0 + ty + i) * C + c0 + tx];
  __syncthreads();
  for (int i = 0; i < 32; i += 8) {
    float v = tile[tx][ty + i];
    uint16_t hi = f2bf(v);
    out[(size_t)(c0 + ty + i) * R + r0 + tx] = hi;
    if (outlo)
      outlo[(size_t)(c0 + ty + i) * R + r0 + tx] = f2bf(v - bf2f(hi));
  }
}

// ---------------- elementwise cast fp32 -> bf16 ----------------
__global__ __launch_bounds__(256) void k_cast_bf16(
    const float* __restrict__ in, uint16_t* __restrict__ out, long n) {
  long i = ((long)blockIdx.x * 256 + threadIdx.x) * 4;
  if (i >= n) return;
  float4 v = *(const float4*)(in + i);
  uint2 pk;
  pk.x = (uint32_t)f2bf(v.x) | ((uint32_t)f2bf(v.y) << 16);
  pk.y = (uint32_t)f2bf(v.z) | ((uint32_t)f2bf(v.w) << 16);
  *(uint2*)(out + i) = pk;
}

// ---------------- LayerNorm row of 1024, fp32 in -> bf16 hi(/lo) out ----------------
__global__ __launch_bounds__(256) void k_layernorm(
    const float* __restrict__ x, const float* __restrict__ g,
    const float* __restrict__ bb, uint16_t* __restrict__ out,
    uint16_t* __restrict__ outlo) {
  int row = blockIdx.x;
  const float* xr = x + (size_t)row * 1024;
  int c = threadIdx.x * 4;
  float4 v = *(const float4*)(xr + c);
  float s = v.x + v.y + v.z + v.w;
  float s2 = v.x * v.x + v.y * v.y + v.z * v.z + v.w * v.w;
  for (int off = 32; off; off >>= 1) {
    s += __shfl_down(s, off, 64);
    s2 += __shfl_down(s2, off, 64);
  }
  __shared__ float ps[4], qs[4];
  int lane = threadIdx.x & 63, wv = threadIdx.x >> 6;
  if (!lane) { ps[wv] = s; qs[wv] = s2; }
  __syncthreads();
  float S = ps[0] + ps[1] + ps[2] + ps[3];
  float S2 = qs[0] + qs[1] + qs[2] + qs[3];
  float mu = S * (1.f / 1024.f);
  float var = S2 * (1.f / 1024.f) - mu * mu;
  float rinv = rsqrtf(var + 1e-5f);
  const float* vv = (const float*)&v;
  uint16_t o[4], ol[4];
#pragma unroll
  for (int j = 0; j < 4; j++) {
    float y = (vv[j] - mu) * rinv * g[c + j] + bb[c + j];
    o[j] = f2bf(y);
    ol[j] = f2bf(y - bf2f(o[j]));
  }
  uint2 pk;
  pk.x = (uint32_t)o[0] | ((uint32_t)o[1] << 16);
  pk.y = (uint32_t)o[2] | ((uint32_t)o[3] << 16);
  *(uint2*)(out + (size_t)row * 1024 + c) = pk;
  if (outlo) {
    pk.x = (uint32_t)ol[0] | ((uint32_t)ol[1] << 16);
    pk.y = (uint32_t)ol[2] | ((uint32_t)ol[3] << 16);
    *(uint2*)(outlo + (size_t)row * 1024 + c) = pk;
  }
}

// ======== bf16 MFMA GEMM, BM=64 x BN=128, BK=64 (16 MFMA/barrier-pair), swizzled ========
// EPI bits: 1=bias 2=resid 4=gelu 8=bf16out 16=splitK. Kc must be a multiple of 64.
template <int EPI>
__global__ __launch_bounds__(256) void k_gemm2(
    const uint16_t* __restrict__ A, int lda,
    const uint16_t* __restrict__ Bt, int ldb,
    void* __restrict__ Cout, int ldc,
    const float* __restrict__ bias,
    const float* __restrict__ resid,
    int Kc) {
  const int m0 = blockIdx.y * 64, n0 = blockIdx.x * 128;
  const int kt0 = (EPI & 16) ? blockIdx.z * Kc : 0;
  __shared__ __align__(16) uint16_t As[64 * 64];    // 8 KB
  __shared__ __align__(16) uint16_t Bs[128 * 64];   // 16 KB
  const int t = threadIdx.x, l = t & 63, w = t >> 6;
  const int lg = l >> 4, lr = l & 15;

  const int rS = t >> 3, cS = t & 7;
  const int csS = cS ^ (rS & 7);
  const uint16_t* pa1 = A + (size_t)(m0 + rS) * lda + kt0 + csS * 8;
  const uint16_t* pa2 = pa1 + (size_t)32 * lda;
  const uint16_t* pb1 = Bt + (size_t)(n0 + rS) * ldb + kt0 + csS * 8;
  const uint16_t* pb2 = pb1 + (size_t)32 * ldb;
  const uint16_t* pb3 = pb1 + (size_t)64 * ldb;
  const uint16_t* pb4 = pb1 + (size_t)96 * ldb;
  uint16_t* la1 = As + w * 512;
  uint16_t* la2 = As + 2048 + w * 512;
  uint16_t* lb1 = Bs + w * 512;
  uint16_t* lb2 = Bs + 2048 + w * 512;
  uint16_t* lb3 = Bs + 4096 + w * 512;
  uint16_t* lb4 = Bs + 6144 + w * 512;

  int offA[2][4], offB[2][2];
#pragma unroll
  for (int kk = 0; kk < 2; kk++) {
#pragma unroll
    for (int i = 0; i < 4; i++) {
      int row = i * 16 + lr;
      offA[kk][i] = row * 64 + (((kk * 4 + lg) ^ (row & 7)) * 8);
    }
#pragma unroll
    for (int j = 0; j < 2; j++) {
      int row = w * 32 + j * 16 + lr;
      offB[kk][j] = row * 64 + (((kk * 4 + lg) ^ (row & 7)) * 8);
    }
  }

  f32x4 acc[4][2] = {};
  for (int kt = 0; kt < Kc; kt += 64) {
    __syncthreads();
    gload16(pa1, la1); gload16(pa2, la2);
    gload16(pb1, lb1); gload16(pb2, lb2);
    gload16(pb3, lb3); gload16(pb4, lb4);
    pa1 += 64; pa2 += 64; pb1 += 64; pb2 += 64; pb3 += 64; pb4 += 64;
    __syncthreads();
#pragma unroll
    for (int kk = 0; kk < 2; kk++) {
      bf16x8 af[4], bfr[2];
#pragma unroll
      for (int i = 0; i < 4; i++) af[i] = as_bf16x8(*(const uint4*)(As + offA[kk][i]));
#pragma unroll
      for (int j = 0; j < 2; j++) bfr[j] = as_bf16x8(*(const uint4*)(Bs + offB[kk][j]));
#pragma unroll
      for (int i = 0; i < 4; i++)
#pragma unroll
        for (int j = 0; j < 2; j++)
          acc[i][j] = mfma16(af[i], bfr[j], acc[i][j]);
    }
  }
  const size_t zoff = (EPI & 16) ? (size_t)blockIdx.z * gridDim.y * 64 * ldc : 0;
#pragma unroll
  for (int i = 0; i < 4; i++)
#pragma unroll
    for (int j = 0; j < 2; j++)
#pragma unroll
      for (int r = 0; r < 4; r++) {
        int row = m0 + i * 16 + lg * 4 + r;
        int col = n0 + w * 32 + j * 16 + lr;
        float v = acc[i][j][r];
        if constexpr (EPI & 16) {
          ((float*)Cout)[zoff + (size_t)row * ldc + col] = v;
        } else {
          if constexpr (EPI & 1) v += bias[col];
          if constexpr (EPI & 4) v = gelu_tanh(v);
          if constexpr (EPI & 2) v += resid[(size_t)row * ldc + col];
          if constexpr (EPI & 8)
            ((uint16_t*)Cout)[(size_t)row * ldc + col] = f2bf(v);
          else
            ((float*)Cout)[(size_t)row * ldc + col] = v;
        }
      }
}

// ======== sims GEMM: BM=64 x BN=128, BK=64, bf16 out, batched (z in {0,1}) ========
__global__ __launch_bounds__(256) void k_gemm_sims(
    const uint16_t* __restrict__ A,
    const uint16_t* __restrict__ Bt,
    uint16_t* __restrict__ Cout) {
  const int m0 = blockIdx.y * 64, n0 = blockIdx.x * 128;
  A += (size_t)blockIdx.z * 1024 * 3072;
  Bt += (size_t)blockIdx.z * 8192 * 1024;
  __shared__ __align__(16) uint16_t As[64 * 64];    // 8 KB
  __shared__ __align__(16) uint16_t Bs[128 * 64];   // 16 KB
  const int t = threadIdx.x, l = t & 63, w = t >> 6;
  const int lg = l >> 4, lr = l & 15;

  const int rS = t >> 3, cS = t & 7;
  const int csS = cS ^ (rS & 7);
  const uint16_t* pa1 = A + (size_t)(m0 + rS) * 3072 + csS * 8;
  const uint16_t* pa2 = pa1 + 32 * 3072;
  const uint16_t* pb1 = Bt + (size_t)(n0 + rS) * 1024 + csS * 8;
  const uint16_t* pb2 = pb1 + 32 * 1024;
  const uint16_t* pb3 = pb1 + 64 * 1024;
  const uint16_t* pb4 = pb1 + 96 * 1024;
  uint16_t* la1 = As + w * 512;
  uint16_t* la2 = As + 2048 + w * 512;
  uint16_t* lb1 = Bs + w * 512;
  uint16_t* lb2 = Bs + 2048 + w * 512;
  uint16_t* lb3 = Bs + 4096 + w * 512;
  uint16_t* lb4 = Bs + 6144 + w * 512;

  int offA[2][4], offB[2][2];
#pragma unroll
  for (int kk = 0; kk < 2; kk++) {
#pragma unroll
    for (int i = 0; i < 4; i++) {
      int row = i * 16 + lr;
      offA[kk][i] = row * 64 + (((kk * 4 + lg) ^ (row & 7)) * 8);
    }
#pragma unroll
    for (int j = 0; j < 2; j++) {
      int row = w * 32 + j * 16 + lr;
      offB[kk][j] = row * 64 + (((kk * 4 + lg) ^ (row & 7)) * 8);
    }
  }

  f32x4 acc[4][2] = {};
  for (int kt = 0; kt < 1024; kt += 64) {
    __syncthreads();
    gload16(pa1, la1); gload16(pa2, la2);
    gload16(pb1, lb1); gload16(pb2, lb2);
    gload16(pb3, lb3); gload16(pb4, lb4);
    pa1 += 64; pa2 += 64; pb1 += 64; pb2 += 64; pb3 += 64; pb4 += 64;
    __syncthreads();
#pragma unroll
    for (int kk = 0; kk < 2; kk++) {
      bf16x8 af[4], bfr[2];
#pragma unroll
      for (int i = 0; i < 4; i++) af[i] = as_bf16x8(*(const uint4*)(As + offA[kk][i]));
#pragma unroll
      for (int j = 0; j < 2; j++) bfr[j] = as_bf16x8(*(const uint4*)(Bs + offB[kk][j]));
#pragma unroll
      for (int i = 0; i < 4; i++)
#pragma unroll
        for (int j = 0; j < 2; j++)
          acc[i][j] = mfma16(af[i], bfr[j], acc[i][j]);
    }
  }
  const size_t zoff = (size_t)blockIdx.z * 1024 * 8192;
#pragma unroll
  for (int i = 0; i < 4; i++)
#pragma unroll
    for (int j = 0; j < 2; j++)
#pragma unroll
      for (int r = 0; r < 4; r++) {
        int row = m0 + i * 16 + lg * 4 + r;
        int col = n0 + w * 32 + j * 16 + lr;
        Cout[zoff + (size_t)row * 8192 + col] = f2bf(acc[i][j][r]);
      }
}

// ------- split-precision GEMM (3-term), BM=64 x BN=128, BK=64, gload_lds, swizzled -------
__global__ __launch_bounds__(256) void k_gemm_split2(
    const uint16_t* __restrict__ Ah, const uint16_t* __restrict__ Al, int lda,
    const uint16_t* __restrict__ Bh, const uint16_t* __restrict__ Bl, int ldb,
    uint16_t* __restrict__ Ch, uint16_t* __restrict__ Cl, int ldc,
    const float* __restrict__ bias, int Kd) {
  const int m0 = blockIdx.y * 64, n0 = blockIdx.x * 128;
  __shared__ __align__(16) uint16_t Ahs[64 * 64];
  __shared__ __align__(16) uint16_t Als[64 * 64];
  __shared__ __align__(16) uint16_t Bhs[128 * 64];
  __shared__ __align__(16) uint16_t Bls[128 * 64];
  const int t = threadIdx.x, l = t & 63, w = t >> 6;
  const int lg = l >> 4, lr = l & 15;

  const int rS = t >> 3, cS = t & 7;
  const int csS = cS ^ (rS & 7);
  const size_t ao1 = (size_t)(m0 + rS) * lda + csS * 8;
  const size_t bo1 = (size_t)(n0 + rS) * ldb + csS * 8;
  const uint16_t* pah1 = Ah + ao1; const uint16_t* pah2 = pah1 + (size_t)32 * lda;
  const uint16_t* pal1 = Al + ao1; const uint16_t* pal2 = pal1 + (size_t)32 * lda;
  const uint16_t* pbh1 = Bh + bo1; const uint16_t* pbh2 = pbh1 + (size_t)32 * ldb;
  const uint16_t* pbh3 = pbh1 + (size_t)64 * ldb; const uint16_t* pbh4 = pbh1 + (size_t)96 * ldb;
  const uint16_t* pbl1 = Bl + bo1; const uint16_t* pbl2 = pbl1 + (size_t)32 * ldb;
  const uint16_t* pbl3 = pbl1 + (size_t)64 * ldb; const uint16_t* pbl4 = pbl1 + (size_t)96 * ldb;
  uint16_t* lah1 = Ahs + w * 512; uint16_t* lah2 = Ahs + 2048 + w * 512;
  uint16_t* lal1 = Als + w * 512; uint16_t* lal2 = Als + 2048 + w * 512;
  uint16_t* lbh1 = Bhs + w * 512; uint16_t* lbh2 = Bhs + 2048 + w * 512;
  uint16_t* lbh3 = Bhs + 4096 + w * 512; uint16_t* lbh4 = Bhs + 6144 + w * 512;
  uint16_t* lbl1 = Bls + w * 512; uint16_t* lbl2 = Bls + 2048 + w * 512;
  uint16_t* lbl3 = Bls + 4096 + w * 512; uint16_t* lbl4 = Bls + 6144 + w * 512;

  int offA[2][4], offB[2][2];
#pragma unroll
  for (int kk = 0; kk < 2; kk++) {
#pragma unroll
    for (int i = 0; i < 4; i++) {
      int row = i * 16 + lr;
      offA[kk][i] = row * 64 + (((kk * 4 + lg) ^ (row & 7)) * 8);
    }
#pragma unroll
    for (int j = 0; j < 2; j++) {
      int row = w * 32 + j * 16 + lr;
      offB[kk][j] = row * 64 + (((kk * 4 + lg) ^ (row & 7)) * 8);
    }
  }

  f32x4 acc[4][2] = {};
  for (int kt = 0; kt < Kd; kt += 64) {
    __syncthreads();
    gload16(pah1, lah1); gload16(pah2, lah2);
    gload16(pal1, lal1); gload16(pal2, lal2);
    gload16(pbh1, lbh1); gload16(pbh2, lbh2);
    gload16(pbh3, lbh3); gload16(pbh4, lbh4);
    gload16(pbl1, lbl1); gload16(pbl2, lbl2);
    gload16(pbl3, lbl3); gload16(pbl4, lbl4);
    pah1 += 64; pah2 += 64; pal1 += 64; pal2 += 64;
    pbh1 += 64; pbh2 += 64; pbh3 += 64; pbh4 += 64;
    pbl1 += 64; pbl2 += 64; pbl3 += 64; pbl4 += 64;
    __syncthreads();
#pragma unroll
    for (int kk = 0; kk < 2; kk++) {
      bf16x8 ah[4], al[4], bh[2], bl[2];
#pragma unroll
      for (int i = 0; i < 4; i++) {
        ah[i] = as_bf16x8(*(const uint4*)(Ahs + offA[kk][i]));
        al[i] = as_bf16x8(*(const uint4*)(Als + offA[kk][i]));
      }
#pragma unroll
      for (int j = 0; j < 2; j++) {
        bh[j] = as_bf16x8(*(const uint4*)(Bhs + offB[kk][j]));
        bl[j] = as_bf16x8(*(const uint4*)(Bls + offB[kk][j]));
      }
#pragma unroll
      for (int i = 0; i < 4; i++)
#pragma unroll
        for (int j = 0; j < 2; j++) {
          acc[i][j] = mfma16(ah[i], bh[j], acc[i][j]);
          acc[i][j] = mfma16(ah[i], bl[j], acc[i][j]);
          acc[i][j] = mfma16(al[i], bh[j], acc[i][j]);
        }
    }
  }
#pragma unroll
  for (int i = 0; i < 4; i++)
#pragma unroll
    for (int j = 0; j < 2; j++)
#pragma unroll
      for (int r = 0; r < 4; r++) {
        int row = m0 + i * 16 + lg * 4 + r;
        int col = n0 + w * 32 + j * 16 + lr;
        float v = acc[i][j][r] + bias[col];
        uint16_t hi = f2bf(v);
        Ch[(size_t)row * ldc + col] = hi;
        Cl[(size_t)row * ldc + col] = f2bf(v - bf2f(hi));
      }
}

// ---------------- split-K merge: out = sum(parts) + bias + resid (f32) ----------------
template <int NP>
__global__ __launch_bounds__(256) void k_merge(
    const float* __restrict__ parts, const float* __restrict__ bias,
    const float* __restrict__ resid, float* __restrict__ out) {
  int row = blockIdx.x, c = threadIdx.x * 4;
  size_t off = (size_t)row * 1024 + c;
  float4 s = *(const float4*)(resid + off);
  float4 bv = *(const float4*)(bias + c);
  s.x += bv.x; s.y += bv.y; s.z += bv.z; s.w += bv.w;
#pragma unroll
  for (int z = 0; z < NP; z++) {
    float4 pv = *(const float4*)(parts + (size_t)z * 2048 * 1024 + off);
    s.x += pv.x; s.y += pv.y; s.z += pv.z; s.w += pv.w;
  }
  *(float4*)(out + off) = s;
}

// -------- top-40 superset by bf16 sims (16-bit key search) -> fp32 rerank -> top-32 --------
// grid 2048: block = z*1024 + row (both batches in one launch).
__global__ __launch_bounds__(256) void k_topk2(
    const uint16_t* __restrict__ simsb,   // bf16 [2][1024][8192]
    const uint16_t* __restrict__ qkvh_b,  // [2048][3072]
    const uint16_t* __restrict__ qkvl_b,
    const float* __restrict__ memk_b,     // fp32 [2][8192][1024]
    int* __restrict__ idx_out,            // [2048][32]
    float* __restrict__ mlogh) {          // [2048][32][16]
  int grow = blockIdx.x;                  // global row 0..2047
  int z = grow >> 10;
  int t = threadIdx.x;
  const uint16_t* s16 = simsb + (size_t)grow * 8192;
  const float* memk = memk_b + (size_t)z * 8192 * 1024;
  unsigned key[32];
#pragma unroll
  for (int k = 0; k < 4; k++) {
    uint4 u = *(const uint4*)(s16 + t * 8 + k * 2048);
    const uint16_t* pu = (const uint16_t*)&u;
#pragma unroll
    for (int j = 0; j < 8; j++) key[k * 8 + j] = mono16(pu[j]);
  }
  __shared__ int partial[2][4];   // double-buffered -> ONE barrier per iteration
  __shared__ int cnt_s;
  __shared__ int sidx[40];
  __shared__ float qs[1024];
  __shared__ float hval[40][16];
  int lane = t & 63, wv = t >> 6;
  // phase 1: threshold for top-40 superset — 16-bit key space, 16 iterations
  unsigned lo = 0u, hi = 0xFFFFu;
  for (int it = 0; it < 16; ++it) {
    unsigned mid = lo + ((hi - lo) >> 1);
    int c = 0;
#pragma unroll
    for (int i = 0; i < 32; i++) c += (key[i] > mid) ? 1 : 0;
    for (int off = 32; off; off >>= 1) c += __shfl_down(c, off, 64);
    if (!lane) partial[it & 1][wv] = c;
    __syncthreads();
    int tot = partial[it & 1][0] + partial[it & 1][1] +
              partial[it & 1][2] + partial[it & 1][3];
    if (tot >= 40) lo = mid + 1; else hi = mid;
  }
  unsigned T = lo;
  if (t == 0) cnt_s = 0;
  __syncthreads();
#pragma unroll
  for (int i = 0; i < 32; i++)
    if (key[i] > T) {
      int p = atomicAdd(&cnt_s, 1);
      if (p < 40) sidx[p] = t * 8 + (i >> 3) * 2048 + (i & 7);
    }
  __syncthreads();
#pragma unroll
  for (int i = 0; i < 32; i++)
    if (key[i] == T) {
      int p = atomicAdd(&cnt_s, 1);
      if (p < 40) sidx[p] = t * 8 + (i >> 3) * 2048 + (i & 7);
    }
  // phase 2: stage fp32 q (hi+lo) into LDS
  {
    int c4 = t * 4;
    const uint16_t* qh = qkvh_b + (size_t)grow * 3072;
    const uint16_t* ql = qkvl_b + (size_t)grow * 3072;
    uint2 uh = *(const uint2*)(qh + c4);
    uint2 ul = *(const uint2*)(ql + c4);
    qs[c4 + 0] = bf2f(uh.x & 0xFFFF) + bf2f(ul.x & 0xFFFF);
    qs[c4 + 1] = bf2f(uh.x >> 16) + bf2f(ul.x >> 16);
    qs[c4 + 2] = bf2f(uh.y & 0xFFFF) + bf2f(ul.y & 0xFFFF);
    qs[c4 + 3] = bf2f(uh.y >> 16) + bf2f(ul.y >> 16);
  }
  __syncthreads();
  // phase 3: exact fp32 per-head dots, wave-per-candidate COALESCED gather (10/wave).
  {
    float4 qreg[4];
#pragma unroll
    for (int i = 0; i < 4; i++) qreg[i] = *(const float4*)(qs + i * 256 + lane * 4);
    for (int cc = 0; cc < 10; ++cc) {
      int c = wv * 10 + cc;
      const float* kp = memk + (size_t)sidx[c] * 1024;
#pragma unroll
      for (int i = 0; i < 4; ++i) {
        float4 kv = *(const float4*)(kp + i * 256 + lane * 4);
        float pband = kv.x * qreg[i].x + kv.y * qreg[i].y +
                      kv.z * qreg[i].z + kv.w * qreg[i].w;
        pband += __shfl_xor(pband, 1, 64);
        pband += __shfl_xor(pband, 2, 64);
        pband += __shfl_xor(pband, 4, 64);
        pband += __shfl_xor(pband, 8, 64);
        if ((lane & 15) == 0) hval[c][i * 4 + (lane >> 4)] = pband;
      }
    }
  }
  __syncthreads();
  // phase 4: wave 0 selects exact top-32 by full dot (lanes >= 40 masked out)
  if (wv == 0) {
    float full = 0.f;
    if (t < 40) {
#pragma unroll
      for (int i = 0; i < 16; i++) full += hval[t][i];
    }
    unsigned k2 = (t < 40) ? mono_key(full) : 0u;
    unsigned lo2 = 0u, hi2 = 0xFFFFFFFFu;
    for (int it = 0; it < 32; ++it) {
      unsigned mid = lo2 + ((hi2 - lo2) >> 1);
      int c = __popcll(__ballot(k2 > mid));
      if (c >= 32) lo2 = mid + 1; else hi2 = mid;
    }
    unsigned T2 = lo2;
    unsigned long long m1 = __ballot(k2 > T2);
    unsigned long long m2 = __ballot(k2 == T2);
    int n1 = __popcll(m1);
    unsigned long long lt = ((unsigned long long)1 << t) - 1;
    int pos = 99;
    if (k2 > T2) pos = __popcll(m1 & lt);
    else if (k2 == T2 && t < 40) pos = n1 + __popcll(m2 & lt);
    if (pos < 32) {
      idx_out[(size_t)grow * 32 + pos] = sidx[t];
#pragma unroll
      for (int i = 0; i < 16; i++)
        mlogh[((size_t)grow * 32 + pos) * 16 + i] = hval[t][i] * 0.125f;
    }
  }
}

// ---------------- causal flash attention, KV-split, LDS-shared K/V staging ----------------
__global__ __launch_bounds__(256) void k_flash(
    const uint16_t* __restrict__ qkvh,
    const uint16_t* __restrict__ qkvl,
    float* __restrict__ pacc,      // [4][32][1024][64]
    float* __restrict__ pm,        // [4][32][1024]
    float* __restrict__ pl) {      // [4][32][1024]
  const int qt = blockIdx.x, chk = blockIdx.y, bh = blockIdx.z;
  const int cbase = chk * 256;
  if (cbase >= (qt + 1) * 64) return;
  const int b = bh >> 4, h = bh & 15;
  const int t = threadIdx.x, lane = t & 63, w = t >> 6;
  const int lg = lane >> 4, lr = lane & 15;
  const int q0 = qt * 64 + w * 16;
  const size_t rowb = (size_t)b * 1024;
  __shared__ __align__(16) uint16_t Kh[2048];   // [32 kv][64 dh] (swizzled 16B chunks)
  __shared__ __align__(16) uint16_t Kl[2048];
  __shared__ __align__(16) uint16_t Vs[2048];
  __shared__ __align__(16) uint16_t Pl[4][16][40];

  bf16x8 qh[2], qlo[2];
  {
    const uint16_t* qph = qkvh + (rowb + q0 + lr) * 3072 + h * 64;
    const uint16_t* qpl = qkvl + (rowb + q0 + lr) * 3072 + h * 64;
    qh[0] = as_bf16x8(*(const uint4*)(qph + lg * 8));
    qh[1] = as_bf16x8(*(const uint4*)(qph + 32 + lg * 8));
    qlo[0] = as_bf16x8(*(const uint4*)(qpl + lg * 8));
    qlo[1] = as_bf16x8(*(const uint4*)(qpl + 32 + lg * 8));
  }
  f32x4 acc[4] = {};
  float mrow[4], lrowv[4];
#pragma unroll
  for (int r = 0; r < 4; r++) { mrow[r] = -1e30f; lrowv[r] = 0.f; }

  const int lim = min(cbase + 256, q0 + 16);        // per-wave compute limit
  const int blim = min(cbase + 256, (qt + 1) * 64); // block-uniform staging limit

  const int sr = t >> 3, sc = t & 7;
  const int scs = sc ^ (sr & 7);
  const uint16_t* gkh = qkvh + (rowb + sr) * 3072 + 1024 + h * 64 + scs * 8;
  const uint16_t* gkl = qkvl + (rowb + sr) * 3072 + 1024 + h * 64 + scs * 8;
  const uint16_t* gv  = qkvh + (rowb + sr) * 3072 + 2048 + h * 64 + scs * 8;
  uint16_t* lkh = Kh + w * 512;
  uint16_t* lkl = Kl + w * 512;
  uint16_t* lv  = Vs + w * 512;

  for (int c0 = cbase; c0 < blim; c0 += 32) {
    const size_t so = (size_t)c0 * 3072;
    gload16(gkh + so, lkh);
    gload16(gkl + so, lkl);
    gload16(gv + so, lv);
    __syncthreads();
    if (c0 < lim) {
      f32x4 sf[2];
#pragma unroll
      for (int n = 0; n < 2; n++) {
        const int row = n * 16 + lr;
        const int rb = row * 64;
        const int x0 = ((lg) ^ (row & 7)) * 8;
        const int x1 = ((4 + lg) ^ (row & 7)) * 8;
        bf16x8 kh0 = as_bf16x8(*(const uint4*)(Kh + rb + x0));
        bf16x8 kh1 = as_bf16x8(*(const uint4*)(Kh + rb + x1));
        bf16x8 kl0 = as_bf16x8(*(const uint4*)(Kl + rb + x0));
        bf16x8 kl1 = as_bf16x8(*(const uint4*)(Kl + rb + x1));
        f32x4 sz = {};
        sz = mfma16(qh[0], kh0, sz);
        sz = mfma16(qh[1], kh1, sz);
        sz = mfma16(qh[0], kl0, sz);
        sz = mfma16(qh[1], kl1, sz);
        sz = mfma16(qlo[0], kh0, sz);
        sz = mfma16(qlo[1], kh1, sz);
        sf[n] = sz;
      }
      float p0[4], p1[4], alpha[4];
#pragma unroll
      for (int r = 0; r < 4; r++) {
        int rowq = q0 + lg * 4 + r;
        int col0 = c0 + lr, col1 = c0 + 16 + lr;
        float s0 = sf[0][r] * 0.125f; if (col0 > rowq) s0 = -1e30f;
        float s1 = sf[1][r] * 0.125f; if (col1 > rowq) s1 = -1e30f;
        float mt = fmaxf(s0, s1);
        mt = fmaxf(mt, __shfl_xor(mt, 1, 64));
        mt = fmaxf(mt, __shfl_xor(mt, 2, 64));
        mt = fmaxf(mt, __shfl_xor(mt, 4, 64));
        mt = fmaxf(mt, __shfl_xor(mt, 8, 64));
        float mnew = fmaxf(mrow[r], mt);
        float a = __expf(mrow[r] - mnew);
        float e0 = __expf(s0 - mnew), e1 = __expf(s1 - mnew);
        float ss = e0 + e1;
        ss += __shfl_xor(ss, 1, 64);
        ss += __shfl_xor(ss, 2, 64);
        ss += __shfl_xor(ss, 4, 64);
        ss += __shfl_xor(ss, 8, 64);
        lrowv[r] = lrowv[r] * a + ss;
        mrow[r] = mnew;
        alpha[r] = a;
        p0[r] = e0; p1[r] = e1;
      }
#pragma unroll
      for (int nv = 0; nv < 4; nv++)
#pragma unroll
        for (int r = 0; r < 4; r++) acc[nv][r] *= alpha[r];
#pragma unroll
      for (int r = 0; r < 4; r++) {
        Pl[w][lg * 4 + r][lr] = f2bf(p0[r]);
        Pl[w][lg * 4 + r][16 + lr] = f2bf(p1[r]);
      }
      bf16x8 pa = as_bf16x8(*(const uint4*)&Pl[w][lr][lg * 8]);
#pragma unroll
      for (int nv = 0; nv < 4; nv++) {
        const int col = nv * 16 + lr;
        const int cc = col >> 3, cl = col & 7;
        uint32_t vv[8];
#pragma unroll
        for (int j = 0; j < 8; j++) {
          int row = lg * 8 + j;
          vv[j] = Vs[row * 64 + ((cc ^ (row & 7)) * 8 + cl)];
        }
        uint4 pk;
        pk.x = vv[0] | (vv[1] << 16);
        pk.y = vv[2] | (vv[3] << 16);
        pk.z = vv[4] | (vv[5] << 16);
        pk.w = vv[6] | (vv[7] << 16);
        acc[nv] = mfma16(pa, as_bf16x8(pk), acc[nv]);
      }
    }
    __syncthreads();
  }
  const size_t base = (size_t)(chk * 32 + bh) * 1024;
#pragma unroll
  for (int nv = 0; nv < 4; nv++)
#pragma unroll
    for (int r = 0; r < 4; r++) {
      int rowq = q0 + lg * 4 + r;
      pacc[(base + rowq) * 64 + nv * 16 + lr] = acc[nv][r];
    }
  if (lr == 0) {
#pragma unroll
    for (int r = 0; r < 4; r++) {
      int rowq = q0 + lg * 4 + r;
      pm[base + rowq] = mrow[r];
      pl[base + rowq] = lrowv[r];
    }
  }
}

// ------- mem attention (precomputed logits) + chunk-merge of local + combine -------
__global__ __launch_bounds__(256) void k_memcombine(
    const float* __restrict__ mlogh,     // [2048][32][16]
    const float* __restrict__ memv,      // f32  [B][8192][1024]
    const int* __restrict__ idx,         // [2048][32]
    const float* __restrict__ pacc,      // [4][32][1024][64]
    const float* __restrict__ pm,        // [4][32][1024]
    const float* __restrict__ pl,        // [4][32][1024]
    const float* __restrict__ gval,
    uint16_t* __restrict__ attnout) {
  int row = blockIdx.x;
  int b = row >> 10, s = row & 1023;
  int qt = s >> 6;
  int nact = (qt >> 2) + 1;
  __shared__ int sidx[32];
  __shared__ float lg[16][32];
  __shared__ float sp[16][32];
  __shared__ float smx[16], ssum[16];
  __shared__ float scl[16][4], Ms[16], Ls[16];
  int t = threadIdx.x;
  if (t < 32) sidx[t] = idx[(size_t)row * 32 + t];
  {
    const float* mp = mlogh + (size_t)row * 512;
#pragma unroll
    for (int rep = 0; rep < 2; rep++) {
      int i = t + rep * 256;
      lg[i & 15][i >> 4] = mp[i];
    }
  }
  __syncthreads();
  if (t < 16) {
    float mx = -1e30f;
#pragma unroll
    for (int j = 0; j < 32; j++) mx = fmaxf(mx, lg[t][j]);
    float su = 0.f;
    for (int j = 0; j < 32; j++) {
      float e = __expf(lg[t][j] - mx);
      sp[t][j] = e; su += e;
    }
    smx[t] = mx; ssum[t] = su;
  } else if (t >= 64 && t < 80) {
    int hh = t - 64;
    float pmv[4];
    float M = -1e30f;
    for (int c = 0; c < nact; c++) {
      pmv[c] = pm[(size_t)(c * 32 + b * 16 + hh) * 1024 + s];
      M = fmaxf(M, pmv[c]);
    }
    float L = 0.f;
    for (int c = 0; c < nact; c++) {
      float e = __expf(pmv[c] - M);
      scl[hh][c] = e;
      L += e * pl[(size_t)(c * 32 + b * 16 + hh) * 1024 + s];
    }
    Ms[hh] = M; Ls[hh] = L;
  }
  __syncthreads();
#pragma unroll
  for (int cc = 0; cc < 4; cc++) {
    int col = t + cc * 256;
    int hh = col >> 6;
    float ma = 0.f;
#pragma unroll
    for (int j = 0; j < 32; j++)
      ma += sp[hh][j] * memv[((size_t)b * 8192 + sidx[j]) * 1024 + col];
    float la = 0.f;
    for (int c = 0; c < nact; c++)
      la += scl[hh][c] *
            pacc[((size_t)(c * 32 + b * 16 + hh) * 1024 + s) * 64 + (col & 63)];
    float ms = Ms[hh], ls = Ls[hh];
    float mm = smx[hh], lmm = ssum[hh];
    float Mx = fmaxf(ms, mm);
    float es = __expf(ms - Mx), em = __expf(mm - Mx);
    float L = es * ls + em * lmm;
    float gh = gval[hh];
    float o = ((1.f - gh) * es * la + gh * em * ma) / L;
    attnout[(size_t)row * 1024 + col] = f2bf(o);
  }
}

extern "C" void kernel_launch(void* const* d_in, const int* in_sizes, int n_in,
                              void* d_out, int out_size, void* d_ws, size_t ws_size,
                              hipStream_t stream) {
  (void)in_sizes; (void)n_in; (void)out_size; (void)ws_size;
  const float* x     = (const float*)d_in[0];
  const float* memkf = (const float*)d_in[1];
  const float* memvf = (const float*)d_in[2];
  const float* gval  = (const float*)d_in[3];
  const float* ln1g  = (const float*)d_in[4];
  const float* ln1b  = (const float*)d_in[5];
  const float* Wattn = (const float*)d_in[6];
  const float* battn = (const float*)d_in[7];
  const float* Wproj = (const float*)d_in[8];
  const float* bproj = (const float*)d_in[9];
  const float* ln2g  = (const float*)d_in[10];
  const float* ln2b  = (const float*)d_in[11];
  const float* Wfc   = (const float*)d_in[12];
  const float* bfc   = (const float*)d_in[13];
  const float* Wout  = (const float*)d_in[14];
  const float* bout  = (const float*)d_in[15];

  char* p = (char*)d_ws;
  auto alloc = [&](size_t bytes) -> char* {
    char* r = p;
    p += (bytes + 255) & ~(size_t)255;
    return r;
  };
  uint16_t* h_hi    = (uint16_t*)alloc(2048ull * 1024 * 2);   // reused as h2
  uint16_t* h_lo    = (uint16_t*)alloc(2048ull * 1024 * 2);
  uint16_t* WattnTh = (uint16_t*)alloc(3072ull * 1024 * 2);
  uint16_t* WattnTl = (uint16_t*)alloc(3072ull * 1024 * 2);
  uint16_t* WprojT  = (uint16_t*)alloc(1024ull * 1024 * 2);
  uint16_t* WfcT    = (uint16_t*)alloc(4096ull * 1024 * 2);
  uint16_t* WoutT   = (uint16_t*)alloc(1024ull * 4096 * 2);
  uint16_t* memk_bf = (uint16_t*)alloc(2ull * 8192 * 1024 * 2);  // reused: splitK parts
  uint16_t* qkv_hi  = (uint16_t*)alloc(2048ull * 3072 * 2);
  uint16_t* qkv_lo  = (uint16_t*)alloc(2048ull * 3072 * 2);
  float*    sims    = (float*)alloc(1024ull * 8192 * 4);  // bf16[2][1024][8192]; reused: pacc, ffn1
  int*      idx     = (int*)alloc(2048ull * 32 * 4);
  float*    mlogh   = (float*)alloc(2048ull * 32 * 16 * 4);
  float*    pm      = (float*)alloc(4ull * 32 * 1024 * 4);
  float*    pl      = (float*)alloc(4ull * 32 * 1024 * 4);
  float*    h1      = (float*)alloc(2048ull * 1024 * 4);
  uint16_t* attn_bf = (uint16_t*)alloc(2048ull * 1024 * 2);
  uint16_t* h2_bf   = h_hi;
  uint16_t* simsb   = (uint16_t*)sims;   // bf16 sims, both batches (32 MiB)
  float*    pacc    = sims;              // alive: after topk2 .. memcombine
  uint16_t* ffn1    = (uint16_t*)sims;   // alive: after memcombine
  float*    parts   = (float*)memk_bf;   // alive: after sims GEMM

  // weight prep
  k_transpose_cast<<<dim3(96, 32), 256, 0, stream>>>(Wattn, WattnTh, WattnTl, 1024, 3072);
  k_transpose_cast<<<dim3(32, 32), 256, 0, stream>>>(Wproj, WprojT, nullptr, 1024, 1024);
  k_transpose_cast<<<dim3(128, 32), 256, 0, stream>>>(Wfc, WfcT, nullptr, 1024, 4096);
  k_transpose_cast<<<dim3(32, 128), 256, 0, stream>>>(Wout, WoutT, nullptr, 4096, 1024);
  k_cast_bf16<<<16384, 256, 0, stream>>>(memkf, memk_bf, 2l * 8192 * 1024);

  // LN1 + QKV (split precision, BK=64)
  k_layernorm<<<2048, 256, 0, stream>>>(x, ln1g, ln1b, h_hi, h_lo);
  k_gemm_split2<<<dim3(24, 32), 256, 0, stream>>>(h_hi, h_lo, 1024, WattnTh, WattnTl, 1024,
                                                  qkv_hi, qkv_lo, 3072, battn, 1024);
  // sims (bf16 out, BOTH batches, BK=64) + batched exact-rerank topk
  k_gemm_sims<<<dim3(64, 16, 2), 256, 0, stream>>>(qkv_hi, memk_bf, simsb);
  k_topk2<<<2048, 256, 0, stream>>>(simsb, qkv_hi, qkv_lo, memkf, idx, mlogh);
  // attention (KV-split flash with LDS-shared staging; sims region now free -> pacc)
  k_flash<<<dim3(16, 4, 32), 256, 0, stream>>>(qkv_hi, qkv_lo, pacc, pm, pl);
  k_memcombine<<<2048, 256, 0, stream>>>(mlogh, memvf, idx, pacc, pm, pl, gval, attn_bf);
  // proj + residual  (split-K=2 -> parts, then merge with bias + x)
  k_gemm2<16><<<dim3(8, 32, 2), 256, 0, stream>>>(attn_bf, 1024, WprojT, 1024,
                                                  parts, 1024, nullptr, nullptr, 512);
  k_merge<2><<<2048, 256, 0, stream>>>(parts, bproj, x, h1);
  // FFN (pacc region now free -> ffn1)
  k_layernorm<<<2048, 256, 0, stream>>>(h1, ln2g, ln2b, h2_bf, nullptr);
  k_gemm2<13><<<dim3(32, 32), 256, 0, stream>>>(h2_bf, 1024, WfcT, 1024,
                                                ffn1, 4096, bfc, nullptr, 1024);
  // out GEMM (K=4096, split-K=4 -> parts, merge with bias + h1 residual)
  k_gemm2<16><<<dim3(8, 32, 4), 256, 0, stream>>>(ffn1, 4096, WoutT, 4096,
                                                  parts, 1024, nullptr, nullptr, 1024);
  k_merge<4><<<2048, 256, 0, stream>>>(parts, bout, h1, (float*)d_out);
}